// Round 1
// baseline (1019.214 us; speedup 1.0000x reference)
//
#include <hip/hip_runtime.h>
#include <hip/hip_bf16.h>

#define G_   20000
#define B_   256
#define NNZ_ 640000

typedef float f4 __attribute__((ext_vector_type(4)));

// ---------------- zero scratch (capture-safe, no memset) ----------------
__global__ __launch_bounds__(256) void zero_kernel(unsigned int* p, int n) {
    int i = blockIdx.x * 256 + threadIdx.x;
    if (i < n) p[i] = 0u;
}

// ---------------- embed + transpose: [B,G] -> [G,B], relu(a*x+b) --------
__global__ __launch_bounds__(256) void embed_kernel(
        const float* __restrict__ xsamp, const float* __restrict__ xtf,
        const float* __restrict__ em, const float* __restrict__ bm,
        const float* __restrict__ ee, const float* __restrict__ be,
        float* __restrict__ X0s, float* __restrict__ X0t) {
    __shared__ float lds[64][65];
    const int t  = threadIdx.x;
    const int gb = blockIdx.x * 64, bb = blockIdx.y * 64;
    const float a_m = em[0], c_m = bm[0], a_e = ee[0], c_e = be[0];

    // ---- x_sample ----
    {
        int gl = t & 63, bl0 = t >> 6;
#pragma unroll
        for (int r = 0; r < 16; r++) {
            int bl = bl0 + r * 4;
            int g  = gb + gl;
            float v = 0.f;
            if (g < G_) v = xsamp[(size_t)(bb + bl) * G_ + g];
            lds[bl][gl] = fmaxf(a_m * v + c_m, 0.f);
        }
    }
    __syncthreads();
    {
        int bl = t & 63, gl0 = t >> 6;
#pragma unroll
        for (int r = 0; r < 16; r++) {
            int gl = gl0 + r * 4;
            int g  = gb + gl;
            if (g < G_) X0s[(size_t)g * B_ + bb + bl] = lds[bl][gl];
        }
    }
    __syncthreads();
    // ---- x_TF ----
    {
        int gl = t & 63, bl0 = t >> 6;
#pragma unroll
        for (int r = 0; r < 16; r++) {
            int bl = bl0 + r * 4;
            int g  = gb + gl;
            float v = 0.f;
            if (g < G_) v = xtf[(size_t)(bb + bl) * G_ + g];
            lds[bl][gl] = fmaxf(a_e * v + c_e, 0.f);
        }
    }
    __syncthreads();
    {
        int bl = t & 63, gl0 = t >> 6;
#pragma unroll
        for (int r = 0; r < 16; r++) {
            int gl = gl0 + r * 4;
            int g  = gb + gl;
            if (g < G_) X0t[(size_t)g * B_ + bb + bl] = lds[bl][gl];
        }
    }
}

// ---------------- CSR build: histogram ----------------------------------
__global__ __launch_bounds__(256) void hist_kernel(
        const int* __restrict__ rA, const int* __restrict__ rB,
        int* __restrict__ cntA, int* __restrict__ cntB) {
    int i = blockIdx.x * 256 + threadIdx.x;
    if (i < NNZ_) {
        atomicAdd(&cntA[rA[i]], 1);
        atomicAdd(&cntB[rB[i]], 1);
    }
}

// ---------------- CSR build: exclusive scan (one block per matrix) ------
__global__ __launch_bounds__(1024) void scan_kernel(
        const int* __restrict__ cntA, const int* __restrict__ cntB,
        int* __restrict__ rpA, int* __restrict__ rpB,
        int* __restrict__ curA, int* __restrict__ curB) {
    const int* cnt; int* rp; int* cur;
    if (blockIdx.x == 0) { cnt = cntA; rp = rpA; cur = curA; }
    else                 { cnt = cntB; rp = rpB; cur = curB; }
    __shared__ int lds[1024];
    const int t = threadIdx.x;
    const int CH = 20;                       // 1024*20 = 20480 >= G_
    int base = t * CH;
    int loc[CH];
    int s = 0;
#pragma unroll
    for (int i = 0; i < CH; i++) {
        int idx = base + i;
        int v = (idx < G_) ? cnt[idx] : 0;
        loc[i] = s; s += v;
    }
    lds[t] = s;
    __syncthreads();
    for (int off = 1; off < 1024; off <<= 1) {
        int v = lds[t];
        int add = (t >= off) ? lds[t - off] : 0;
        __syncthreads();
        lds[t] = v + add;
        __syncthreads();
    }
    int pre = (t == 0) ? 0 : lds[t - 1];
#pragma unroll
    for (int i = 0; i < CH; i++) {
        int idx = base + i;
        if (idx < G_) { int p = pre + loc[i]; rp[idx] = p; cur[idx] = p; }
    }
    if (t == 1023) rp[G_] = lds[1023];
}

// ---------------- CSR build: scatter -------------------------------------
__global__ __launch_bounds__(256) void scatter_kernel(
        const int* __restrict__ rA, const int* __restrict__ cA, const float* __restrict__ vA,
        const int* __restrict__ rB, const int* __restrict__ cB, const float* __restrict__ vB,
        int* __restrict__ curA, int* __restrict__ curB,
        int* __restrict__ scA, float* __restrict__ svA,
        int* __restrict__ scB, float* __restrict__ svB) {
    int i = blockIdx.x * 256 + threadIdx.x;
    if (i < NNZ_) {
        int r = rA[i]; int p = atomicAdd(&curA[r], 1); scA[p] = cA[i]; svA[p] = vA[i];
        r = rB[i];     p = atomicAdd(&curB[r], 1);     scB[p] = cB[i]; svB[p] = vB[i];
    }
}

// ---------------- SPMM: y = 0.9 * A x, pull CSR, 1 wave per row ----------
// block 64 threads; lane handles 4 consecutive b's (float4). Handles both
// matrices in one launch: blocks [0,G) -> adj, [G,2G) -> adjT.
__global__ __launch_bounds__(64) void spmm_kernel(
        const int* __restrict__ rpA, const int* __restrict__ scA, const float* __restrict__ svA,
        const float* __restrict__ xinA, float* __restrict__ xoutA,
        const int* __restrict__ rpB, const int* __restrict__ scB, const float* __restrict__ svB,
        const float* __restrict__ xinB, float* __restrict__ xoutB) {
    int g = blockIdx.x;
    const int* rp; const int* sc; const float* sv; const float* xin; float* xout;
    if (g < G_) { rp = rpA; sc = scA; sv = svA; xin = xinA; xout = xoutA; }
    else        { g -= G_; rp = rpB; sc = scB; sv = svB; xin = xinB; xout = xoutB; }
    const int t4 = threadIdx.x * 4;
    int beg = rp[g], end = rp[g + 1];
    f4 acc = {0.f, 0.f, 0.f, 0.f};
    int e = beg;
    for (; e + 2 <= end; e += 2) {
        int   c0 = sc[e],  c1 = sc[e + 1];
        float v0 = sv[e],  v1 = sv[e + 1];
        f4 x0 = *(const f4*)(xin + (size_t)c0 * B_ + t4);
        f4 x1 = *(const f4*)(xin + (size_t)c1 * B_ + t4);
        acc += x0 * v0;
        acc += x1 * v1;
    }
    if (e < end) {
        int c = sc[e]; float v = sv[e];
        acc += (*(const f4*)(xin + (size_t)c * B_ + t4)) * v;
    }
    *(f4*)(xout + (size_t)g * B_ + t4) = acc * 0.9f;
}

// ---------------- combine: had[g][b] = (x2s+0.1*x0s)*(x2t+0.1*x0t) -------
__global__ __launch_bounds__(256) void combine_kernel(
        const float* __restrict__ X2s, const float* __restrict__ X0s,
        const float* __restrict__ X2t, const float* __restrict__ X0t,
        float* __restrict__ had) {
    int i = blockIdx.x * 256 + threadIdx.x;   // float4 index, exact grid
    f4 s  = ((const f4*)X2s)[i] + ((const f4*)X0s)[i] * 0.1f;
    f4 tt = ((const f4*)X2t)[i] + ((const f4*)X0t)[i] * 0.1f;
    ((f4*)had)[i] = s * tt;
}

// ---------------- GEMM1: out1[b][o] += sum_g had[g][b] * W1[o][g] --------
// tile 64(o) x 64(b), K-chunked split-K (z dim), 128 threads, 8x4 micro.
__global__ __launch_bounds__(128) void gemm1_kernel(
        const float* __restrict__ had, const float* __restrict__ W1,
        float* __restrict__ out1) {
    __shared__ float a_lds[32][64];   // [k][o]
    __shared__ float b_lds[32][64];   // [k][b]
    const int t  = threadIdx.x;
    const int ob = blockIdx.x * 64;
    const int bb = blockIdx.y * 64;
    int kb = blockIdx.z * 2048;
    int ke = kb + 2048; if (ke > G_) ke = G_;
    const int to = t >> 4;   // 0..7
    const int tb = t & 15;   // 0..15
    float acc[8][4] = {};

    for (int k0 = kb; k0 < ke; k0 += 32) {
        // load W1 tile -> a_lds[k][o]
        {
            int kf = t & 7, o0 = t >> 3;          // o0 0..15
#pragma unroll
            for (int i = 0; i < 4; i++) {
                int o = o0 + i * 16;
                f4 w = *(const f4*)(W1 + (size_t)(ob + o) * G_ + k0 + kf * 4);
#pragma unroll
                for (int c = 0; c < 4; c++) a_lds[kf * 4 + c][o] = w[c];
            }
        }
        // load had tile -> b_lds[k][b]
        {
            int kq = t >> 2, j = t & 3;           // kq 0..31
#pragma unroll
            for (int i = 0; i < 4; i++) {
                int bf = j + i * 4;               // float4 index 0..15
                f4 x = *(const f4*)(had + (size_t)(k0 + kq) * B_ + bb + bf * 4);
                *(f4*)&b_lds[kq][bf * 4] = x;
            }
        }
        __syncthreads();
#pragma unroll 4
        for (int kk = 0; kk < 32; kk++) {
            f4 a0v = *(const f4*)&a_lds[kk][to * 8];
            f4 a1v = *(const f4*)&a_lds[kk][to * 8 + 4];
            f4 bv  = *(const f4*)&b_lds[kk][tb * 4];
#pragma unroll
            for (int i = 0; i < 4; i++)
#pragma unroll
                for (int j = 0; j < 4; j++) {
                    acc[i][j]     += a0v[i] * bv[j];
                    acc[i + 4][j] += a1v[i] * bv[j];
                }
        }
        __syncthreads();
    }
#pragma unroll
    for (int i = 0; i < 8; i++) {
        int o = ob + to * 8 + i;
#pragma unroll
        for (int j = 0; j < 4; j++) {
            int b = bb + tb * 4 + j;
            atomicAdd(&out1[(size_t)b * 1024 + o], acc[i][j]);
        }
    }
}

// ---------------- bias + relu on out1 (in place -> h1) -------------------
__global__ __launch_bounds__(256) void bias_relu_kernel(
        float* __restrict__ out1, const float* __restrict__ b1) {
    int i = blockIdx.x * 256 + threadIdx.x;   // exact: 262144
    int o = i & 1023;
    out1[i] = fmaxf(out1[i] + b1[o], 0.f);
}

// ---------------- fused GEMM2 (relu) + GEMM3, one block per batch row ----
__global__ __launch_bounds__(128) void gemm23_kernel(
        const float* __restrict__ h1, const float* __restrict__ W2,
        const float* __restrict__ b2, const float* __restrict__ W3,
        const float* __restrict__ b3, float* __restrict__ out) {
    __shared__ float h1row[1024];
    __shared__ float h2[128];
    const int b = blockIdx.x, t = threadIdx.x;
    *(f4*)&h1row[t * 4]       = *(const f4*)(h1 + (size_t)b * 1024 + t * 4);
    *(f4*)&h1row[512 + t * 4] = *(const f4*)(h1 + (size_t)b * 1024 + 512 + t * 4);
    __syncthreads();
    {
        float acc = b2[t];
        const f4* w  = (const f4*)(W2 + (size_t)t * 1024);
        const f4* hr = (const f4*)h1row;
        for (int k = 0; k < 256; k++) {
            f4 wv = w[k], hv = hr[k];
            acc += wv[0] * hv[0] + wv[1] * hv[1] + wv[2] * hv[2] + wv[3] * hv[3];
        }
        h2[t] = fmaxf(acc, 0.f);
    }
    __syncthreads();
    if (t < 33) {
        float acc = b3[t];
        const f4* w  = (const f4*)(W3 + (size_t)t * 128);
        const f4* hv = (const f4*)h2;
#pragma unroll
        for (int k = 0; k < 32; k++) {
            f4 a = w[k], x = hv[k];
            acc += a[0] * x[0] + a[1] * x[1] + a[2] * x[2] + a[3] * x[3];
        }
        out[b * 33 + t] = acc;
    }
}

extern "C" void kernel_launch(void* const* d_in, const int* in_sizes, int n_in,
                              void* d_out, int out_size, void* d_ws, size_t ws_size,
                              hipStream_t stream) {
    const float* x_sample = (const float*)d_in[0];
    const float* x_TF     = (const float*)d_in[1];
    const int*   adj_rows = (const int*)d_in[2];
    const int*   adj_cols = (const int*)d_in[3];
    const float* adj_vals = (const float*)d_in[4];
    const int*   adjT_rows = (const int*)d_in[5];
    const int*   adjT_cols = (const int*)d_in[6];
    const float* adjT_vals = (const float*)d_in[7];
    const float* emb_mut  = (const float*)d_in[8];
    const float* bias_mut = (const float*)d_in[9];
    const float* emb_exp  = (const float*)d_in[10];
    const float* bias_exp = (const float*)d_in[11];
    const float* W1 = (const float*)d_in[12];
    const float* b1 = (const float*)d_in[13];
    const float* W2 = (const float*)d_in[14];
    const float* b2 = (const float*)d_in[15];
    const float* W3 = (const float*)d_in[16];
    const float* b3 = (const float*)d_in[17];
    float* out = (float*)d_out;

    // ---- workspace layout (total ~134.7 MB) ----
    float* F    = (float*)d_ws;
    float* X0s  = F;                    // 5,120,000 each
    float* X1s  = X0s + 5120000;
    float* X2s  = X1s + 5120000;
    float* X0t  = X2s + 5120000;
    float* X1t  = X0t + 5120000;
    float* X2t  = X1t + 5120000;
    float* out1 = X2t + 5120000;        // 262,144
    float* svA  = out1 + 262144;        // 640,000
    float* svB  = svA + 640000;         // 640,000
    int* I    = (int*)(svB + 640000);
    int* scA  = I;                      // 640,000
    int* scB  = scA + 640000;           // 640,000
    int* cntA = scB + 640000;           // 20,000
    int* cntB = cntA + 20000;           // 20,000 (contiguous with cntA)
    int* rpA  = cntB + 20000;           // 20,001
    int* rpB  = rpA + 20001;            // 20,001
    int* curA = rpB + 20001;            // 20,000
    int* curB = curA + 20000;           // 20,000

    // zero counters + GEMM1 accumulator
    zero_kernel<<<(40000 + 255) / 256, 256, 0, stream>>>((unsigned int*)cntA, 40000);
    zero_kernel<<<(262144 + 255) / 256, 256, 0, stream>>>((unsigned int*)out1, 262144);

    // embedding + transpose to [G,B]
    embed_kernel<<<dim3(313, 4), 256, 0, stream>>>(
        x_sample, x_TF, emb_mut, bias_mut, emb_exp, bias_exp, X0s, X0t);

    // CSR build for adj and adjT
    hist_kernel<<<(NNZ_ + 255) / 256, 256, 0, stream>>>(adj_rows, adjT_rows, cntA, cntB);
    scan_kernel<<<2, 1024, 0, stream>>>(cntA, cntB, rpA, rpB, curA, curB);
    scatter_kernel<<<(NNZ_ + 255) / 256, 256, 0, stream>>>(
        adj_rows, adj_cols, adj_vals, adjT_rows, adjT_cols, adjT_vals,
        curA, curB, scA, svA, scB, svB);

    // K = 2 PPR iterations (both matrices per launch)
    spmm_kernel<<<2 * G_, 64, 0, stream>>>(rpA, scA, svA, X0s, X1s,
                                           rpB, scB, svB, X0t, X1t);
    spmm_kernel<<<2 * G_, 64, 0, stream>>>(rpA, scA, svA, X1s, X2s,
                                           rpB, scB, svB, X1t, X2t);

    // hadamard with +alpha*h residual; write into X1s (free)
    combine_kernel<<<(G_ * B_ / 4) / 256, 256, 0, stream>>>(X2s, X0s, X2t, X0t, X1s);

    // MLP
    gemm1_kernel<<<dim3(16, 4, 10), 128, 0, stream>>>(X1s, W1, out1);
    bias_relu_kernel<<<262144 / 256, 256, 0, stream>>>(out1, b1);
    gemm23_kernel<<<B_, 128, 0, stream>>>(out1, W2, b2, W3, b3, out);
}

// Round 2
// 790.427 us; speedup vs baseline: 1.2894x; 1.2894x over previous
//
#include <hip/hip_runtime.h>
#include <hip/hip_bf16.h>

#define G_   20000
#define B_   256
#define NNZ_ 640000
#define KCH_ 1280      // gemm1 split-K chunk (40 steps of 32; last z does 25)
#define NZ_  16        // split-K factor

typedef float f4 __attribute__((ext_vector_type(4)));
typedef _Float16 h8 __attribute__((ext_vector_type(8)));
typedef _Float16 h4 __attribute__((ext_vector_type(4)));

// ---------------- zero scratch ------------------------------------------
__global__ __launch_bounds__(256) void zero_kernel(unsigned int* p, int n) {
    int i = blockIdx.x * 256 + threadIdx.x;
    if (i < n) p[i] = 0u;
}

// ---------------- embed + transpose: [B,G] -> [G,B], relu(a*x+b) --------
__global__ __launch_bounds__(256) void embed_kernel(
        const float* __restrict__ xsamp, const float* __restrict__ xtf,
        const float* __restrict__ em, const float* __restrict__ bm,
        const float* __restrict__ ee, const float* __restrict__ be,
        float* __restrict__ X0s, float* __restrict__ X0t) {
    __shared__ float lds[64][65];
    const int t  = threadIdx.x;
    const int gb = blockIdx.x * 64, bb = blockIdx.y * 64;
    const float a_m = em[0], c_m = bm[0], a_e = ee[0], c_e = be[0];
    {
        int gl = t & 63, bl0 = t >> 6;
#pragma unroll
        for (int r = 0; r < 16; r++) {
            int bl = bl0 + r * 4;
            int g  = gb + gl;
            float v = 0.f;
            if (g < G_) v = xsamp[(size_t)(bb + bl) * G_ + g];
            lds[bl][gl] = fmaxf(a_m * v + c_m, 0.f);
        }
    }
    __syncthreads();
    {
        int bl = t & 63, gl0 = t >> 6;
#pragma unroll
        for (int r = 0; r < 16; r++) {
            int gl = gl0 + r * 4;
            int g  = gb + gl;
            if (g < G_) X0s[(size_t)g * B_ + bb + bl] = lds[bl][gl];
        }
    }
    __syncthreads();
    {
        int gl = t & 63, bl0 = t >> 6;
#pragma unroll
        for (int r = 0; r < 16; r++) {
            int bl = bl0 + r * 4;
            int g  = gb + gl;
            float v = 0.f;
            if (g < G_) v = xtf[(size_t)(bb + bl) * G_ + g];
            lds[bl][gl] = fmaxf(a_e * v + c_e, 0.f);
        }
    }
    __syncthreads();
    {
        int bl = t & 63, gl0 = t >> 6;
#pragma unroll
        for (int r = 0; r < 16; r++) {
            int gl = gl0 + r * 4;
            int g  = gb + gl;
            if (g < G_) X0t[(size_t)g * B_ + bb + bl] = lds[bl][gl];
        }
    }
}

// ---------------- CSR build ---------------------------------------------
__global__ __launch_bounds__(256) void hist_kernel(
        const int* __restrict__ rA, const int* __restrict__ rB,
        int* __restrict__ cntA, int* __restrict__ cntB) {
    int i = blockIdx.x * 256 + threadIdx.x;
    if (i < NNZ_) {
        atomicAdd(&cntA[rA[i]], 1);
        atomicAdd(&cntB[rB[i]], 1);
    }
}

__global__ __launch_bounds__(1024) void scan_kernel(
        const int* __restrict__ cntA, const int* __restrict__ cntB,
        int* __restrict__ rpA, int* __restrict__ rpB,
        int* __restrict__ curA, int* __restrict__ curB) {
    const int* cnt; int* rp; int* cur;
    if (blockIdx.x == 0) { cnt = cntA; rp = rpA; cur = curA; }
    else                 { cnt = cntB; rp = rpB; cur = curB; }
    __shared__ int lds[1024];
    const int t = threadIdx.x;
    const int CH = 20;
    int base = t * CH;
    int loc[CH];
    int s = 0;
#pragma unroll
    for (int i = 0; i < CH; i++) {
        int idx = base + i;
        int v = (idx < G_) ? cnt[idx] : 0;
        loc[i] = s; s += v;
    }
    lds[t] = s;
    __syncthreads();
    for (int off = 1; off < 1024; off <<= 1) {
        int v = lds[t];
        int add = (t >= off) ? lds[t - off] : 0;
        __syncthreads();
        lds[t] = v + add;
        __syncthreads();
    }
    int pre = (t == 0) ? 0 : lds[t - 1];
#pragma unroll
    for (int i = 0; i < CH; i++) {
        int idx = base + i;
        if (idx < G_) { int p = pre + loc[i]; rp[idx] = p; cur[idx] = p; }
    }
    if (t == 1023) rp[G_] = lds[1023];
}

__global__ __launch_bounds__(256) void scatter_kernel(
        const int* __restrict__ rA, const int* __restrict__ cA, const float* __restrict__ vA,
        const int* __restrict__ rB, const int* __restrict__ cB, const float* __restrict__ vB,
        int* __restrict__ curA, int* __restrict__ curB,
        int* __restrict__ scA, float* __restrict__ svA,
        int* __restrict__ scB, float* __restrict__ svB) {
    int i = blockIdx.x * 256 + threadIdx.x;
    if (i < NNZ_) {
        int r = rA[i]; int p = atomicAdd(&curA[r], 1); scA[p] = cA[i]; svA[p] = vA[i];
        r = rB[i];     p = atomicAdd(&curB[r], 1);     scB[p] = cB[i]; svB[p] = vB[i];
    }
}

// ---------------- SPMM, B-chunked for L2 residency -----------------------
// grid (G/8, 8 chunks, 2 matrices), 256 threads = 4 waves; each half-wave
// owns one row g and 32 batch columns (chunk). x-chunk = 20000*32*4 = 2.56MB
// -> fits the 4MiB per-XCD L2.
__global__ __launch_bounds__(256) void spmm_kernel(
        const int* __restrict__ rpA, const int* __restrict__ scA, const float* __restrict__ svA,
        const float* __restrict__ xinA, float* __restrict__ xoutA,
        const int* __restrict__ rpB, const int* __restrict__ scB, const float* __restrict__ svB,
        const float* __restrict__ xinB, float* __restrict__ xoutB) {
    const int t = threadIdx.x;
    const int wave = t >> 6, lane = t & 63;
    const int half = lane >> 5, cl = lane & 31;
    const int g   = (blockIdx.x * 4 + wave) * 2 + half;
    const int col = blockIdx.y * 32 + cl;
    const int* rp; const int* sc; const float* sv; const float* xin; float* xout;
    if (blockIdx.z == 0) { rp = rpA; sc = scA; sv = svA; xin = xinA; xout = xoutA; }
    else                 { rp = rpB; sc = scB; sv = svB; xin = xinB; xout = xoutB; }
    int beg = rp[g], end = rp[g + 1];
    int n = end - beg;
    int nother = __shfl_xor(n, 32);
    int nmax = n > nother ? n : nother;
    float acc = 0.f;
    int e = 0;
    for (; e + 4 <= nmax; e += 4) {
        int i0 = beg + e, i1 = i0 + 1, i2 = i0 + 2, i3 = i0 + 3;
        int   c0 = sc[i0], c1 = sc[i1], c2 = sc[i2], c3 = sc[i3];
        float v0 = (e + 0 < n) ? sv[i0] : 0.f;
        float v1 = (e + 1 < n) ? sv[i1] : 0.f;
        float v2 = (e + 2 < n) ? sv[i2] : 0.f;
        float v3 = (e + 3 < n) ? sv[i3] : 0.f;
        acc += v0 * xin[(size_t)c0 * B_ + col];
        acc += v1 * xin[(size_t)c1 * B_ + col];
        acc += v2 * xin[(size_t)c2 * B_ + col];
        acc += v3 * xin[(size_t)c3 * B_ + col];
    }
    for (; e < nmax; ++e) {
        int i0 = beg + e;
        int c0 = sc[i0];
        float v0 = (e < n) ? sv[i0] : 0.f;
        acc += v0 * xin[(size_t)c0 * B_ + col];
    }
    xout[(size_t)g * B_ + col] = 0.9f * acc;
}

// ---------------- combine + transpose + f16 cast: -> had[b][g] ----------
__global__ __launch_bounds__(256) void combine_kernel(
        const float* __restrict__ X2s, const float* __restrict__ X0s,
        const float* __restrict__ X2t, const float* __restrict__ X0t,
        _Float16* __restrict__ hadBK) {
    __shared__ float lds[64][65];
    const int t  = threadIdx.x;
    const int gb = blockIdx.x * 64, bb = blockIdx.y * 64;
    {
        int bl = t & 63, gl0 = t >> 6;
#pragma unroll
        for (int r = 0; r < 16; r++) {
            int gl = gl0 + r * 4;
            int g  = gb + gl;
            float val = 0.f;
            if (g < G_) {
                size_t idx = (size_t)g * B_ + bb + bl;
                float s  = X2s[idx] + 0.1f * X0s[idx];
                float tt = X2t[idx] + 0.1f * X0t[idx];
                val = s * tt;
            }
            lds[bl][gl] = val;
        }
    }
    __syncthreads();
    {
        int gl = t & 63, bl0 = t >> 6;
#pragma unroll
        for (int r = 0; r < 16; r++) {
            int bl = bl0 + r * 4;
            int g  = gb + gl;
            if (g < G_) hadBK[(size_t)(bb + bl) * G_ + g] = (_Float16)lds[bl][gl];
        }
    }
}

// ---------------- W1 f32 -> f16 cast -------------------------------------
__global__ __launch_bounds__(256) void w1cast_kernel(
        const float* __restrict__ W1, _Float16* __restrict__ W1h) {
    size_t i = ((size_t)blockIdx.x * 256 + threadIdx.x) * 4;
    f4 v = *(const f4*)(W1 + i);
    h4 h;
    h[0] = (_Float16)v[0]; h[1] = (_Float16)v[1];
    h[2] = (_Float16)v[2]; h[3] = (_Float16)v[3];
    *(h4*)(W1h + i) = h;
}

// ---------------- GEMM1 via MFMA f16: part[z][b][o] ----------------------
// A = had[b][k] (M=b), B = W1h[o][k] (N=o, reads contiguous k per lane).
// Block tile 128(b) x 64(o) x BK=32; 4 waves each 64x32 (4x2 fragments).
// grid (2, 16, NZ_).
__global__ __launch_bounds__(256) void gemm1_kernel(
        const _Float16* __restrict__ hadBK, const _Float16* __restrict__ W1h,
        float* __restrict__ part) {
    __shared__ _Float16 a_lds[128][40];   // stride 80B: 16B aligned, 2-way banks
    __shared__ _Float16 b_lds[64][40];
    const int t    = threadIdx.x;
    const int lane = t & 63, wid = t >> 6;
    const int wm = wid >> 1, wn = wid & 1;
    const int l15 = lane & 15, l4 = lane >> 4;
    const int bb = blockIdx.x * 128;
    const int ob = blockIdx.y * 64;
    const int kb = blockIdx.z * KCH_;
    int kend = kb + KCH_; if (kend > G_) kend = G_;
    const int nsteps = (kend - kb) >> 5;       // 40 or 25 (G_ = 625*32 exact)
    const int ar = t >> 1, ah = t & 1;         // A-stage: row 0..127, half
    const int br = t >> 2, bs = t & 3;         // B-stage: row 0..63, seg
    f4 acc[4][2] = {};
    for (int s = 0; s < nsteps; ++s) {
        const int k0 = kb + s * 32;
        {   // stage A: had rows (b), 32 k each
            const _Float16* src = hadBK + (size_t)(bb + ar) * G_ + k0 + ah * 16;
            *(h8*)&a_lds[ar][ah * 16]     = *(const h8*)(src);
            *(h8*)&a_lds[ar][ah * 16 + 8] = *(const h8*)(src + 8);
        }
        {   // stage B: W1 rows (o)
            const _Float16* src = W1h + (size_t)(ob + br) * G_ + k0 + bs * 8;
            *(h8*)&b_lds[br][bs * 8] = *(const h8*)(src);
        }
        __syncthreads();
        h8 af[4], bf[2];
#pragma unroll
        for (int m = 0; m < 4; m++)
            af[m] = *(const h8*)&a_lds[wm * 64 + m * 16 + l15][l4 * 8];
#pragma unroll
        for (int n = 0; n < 2; n++)
            bf[n] = *(const h8*)&b_lds[wn * 32 + n * 16 + l15][l4 * 8];
#pragma unroll
        for (int m = 0; m < 4; m++)
#pragma unroll
            for (int n = 0; n < 2; n++)
                acc[m][n] = __builtin_amdgcn_mfma_f32_16x16x32_f16(
                    af[m], bf[n], acc[m][n], 0, 0, 0);
        __syncthreads();
    }
    const size_t zoff = (size_t)blockIdx.z * (B_ * 1024);
#pragma unroll
    for (int m = 0; m < 4; m++)
#pragma unroll
        for (int n = 0; n < 2; n++)
#pragma unroll
            for (int j = 0; j < 4; j++) {
                int b = bb + wm * 64 + m * 16 + l4 * 4 + j;
                int o = ob + wn * 32 + n * 16 + l15;
                part[zoff + (size_t)b * 1024 + o] = acc[m][n][j];
            }
}

// ---------------- reduce split-K partials + bias + relu -> h1 ------------
__global__ __launch_bounds__(256) void reduce_kernel(
        const float* __restrict__ part, const float* __restrict__ b1,
        float* __restrict__ h1) {
    int i = blockIdx.x * 256 + threadIdx.x;    // 262144 total
    float s = 0.f;
#pragma unroll
    for (int z = 0; z < NZ_; z++) s += part[(size_t)z * 262144 + i];
    h1[i] = fmaxf(s + b1[i & 1023], 0.f);
}

// ---------------- fused GEMM2 (relu) + GEMM3 -----------------------------
__global__ __launch_bounds__(128) void gemm23_kernel(
        const float* __restrict__ h1, const float* __restrict__ W2,
        const float* __restrict__ b2, const float* __restrict__ W3,
        const float* __restrict__ b3, float* __restrict__ out) {
    __shared__ float h1row[1024];
    __shared__ float h2[128];
    const int b = blockIdx.x, t = threadIdx.x;
    *(f4*)&h1row[t * 4]       = *(const f4*)(h1 + (size_t)b * 1024 + t * 4);
    *(f4*)&h1row[512 + t * 4] = *(const f4*)(h1 + (size_t)b * 1024 + 512 + t * 4);
    __syncthreads();
    {
        float acc = b2[t];
        const f4* w  = (const f4*)(W2 + (size_t)t * 1024);
        const f4* hr = (const f4*)h1row;
        for (int k = 0; k < 256; k++) {
            f4 wv = w[k], hv = hr[k];
            acc += wv[0] * hv[0] + wv[1] * hv[1] + wv[2] * hv[2] + wv[3] * hv[3];
        }
        h2[t] = fmaxf(acc, 0.f);
    }
    __syncthreads();
    if (t < 33) {
        float acc = b3[t];
        const f4* w  = (const f4*)(W3 + (size_t)t * 128);
        const f4* hv = (const f4*)h2;
#pragma unroll
        for (int k = 0; k < 32; k++) {
            f4 a = w[k], x = hv[k];
            acc += a[0] * x[0] + a[1] * x[1] + a[2] * x[2] + a[3] * x[3];
        }
        out[b * 33 + t] = acc;
    }
}

extern "C" void kernel_launch(void* const* d_in, const int* in_sizes, int n_in,
                              void* d_out, int out_size, void* d_ws, size_t ws_size,
                              hipStream_t stream) {
    const float* x_sample = (const float*)d_in[0];
    const float* x_TF     = (const float*)d_in[1];
    const int*   adj_rows = (const int*)d_in[2];
    const int*   adj_cols = (const int*)d_in[3];
    const float* adj_vals = (const float*)d_in[4];
    const int*   adjT_rows = (const int*)d_in[5];
    const int*   adjT_cols = (const int*)d_in[6];
    const float* adjT_vals = (const float*)d_in[7];
    const float* emb_mut  = (const float*)d_in[8];
    const float* bias_mut = (const float*)d_in[9];
    const float* emb_exp  = (const float*)d_in[10];
    const float* bias_exp = (const float*)d_in[11];
    const float* W1 = (const float*)d_in[12];
    const float* b1 = (const float*)d_in[13];
    const float* W2 = (const float*)d_in[14];
    const float* b2 = (const float*)d_in[15];
    const float* W3 = (const float*)d_in[16];
    const float* b3 = (const float*)d_in[17];
    float* out = (float*)d_out;

    // ---- workspace layout (~134.7 MB, with overlays) ----
    float* F    = (float*)d_ws;
    float* X0s  = F;                    // 5,120,000 floats each
    float* X1s  = X0s + 5120000;
    float* X2s  = X1s + 5120000;
    float* X0t  = X2s + 5120000;
    float* X1t  = X0t + 5120000;
    float* X2t  = X1t + 5120000;
    float* h1   = X2t + 5120000;        // 262,144 (was out1)
    float* svA  = h1 + 262144;          // 640,000
    float* svB  = svA + 640000;         // 640,000
    int* I    = (int*)(svB + 640000);
    int* scA  = I;                      // 640,000
    int* scB  = scA + 640000;
    int* cntA = scB + 640000;           // 20,000
    int* cntB = cntA + 20000;
    int* rpA  = cntB + 20000;           // 20,001
    int* rpB  = rpA + 20001;
    int* curA = rpB + 20001;
    int* curB = curA + 20000;
    // overlays (valid by ordering):
    _Float16* hadBK = (_Float16*)X1s;   // 5.12M f16, written by combine (X1s dead)
    _Float16* W1h   = (_Float16*)X2s;   // 20.48M f16 spans X2s+X0t (dead after combine)
    float*    part  = X0s;              // 16 x 262144 f32 (X0s dead after combine)

    zero_kernel<<<(40000 + 255) / 256, 256, 0, stream>>>((unsigned int*)cntA, 40000);

    embed_kernel<<<dim3(313, 4), 256, 0, stream>>>(
        x_sample, x_TF, emb_mut, bias_mut, emb_exp, bias_exp, X0s, X0t);

    hist_kernel<<<(NNZ_ + 255) / 256, 256, 0, stream>>>(adj_rows, adjT_rows, cntA, cntB);
    scan_kernel<<<2, 1024, 0, stream>>>(cntA, cntB, rpA, rpB, curA, curB);
    scatter_kernel<<<(NNZ_ + 255) / 256, 256, 0, stream>>>(
        adj_rows, adj_cols, adj_vals, adjT_rows, adjT_cols, adjT_vals,
        curA, curB, scA, svA, scB, svB);

    // K = 2 PPR iterations, B-chunked for per-XCD L2 residency
    spmm_kernel<<<dim3(2500, 8, 2), 256, 0, stream>>>(
        rpA, scA, svA, X0s, X1s, rpB, scB, svB, X0t, X1t);
    spmm_kernel<<<dim3(2500, 8, 2), 256, 0, stream>>>(
        rpA, scA, svA, X1s, X2s, rpB, scB, svB, X1t, X2t);

    // hadamard + residual, transpose to [b][g], cast f16
    combine_kernel<<<dim3(313, 4), 256, 0, stream>>>(X2s, X0s, X2t, X0t, hadBK);

    // W1 -> f16 (after combine frees X2s/X0t)
    w1cast_kernel<<<20000, 256, 0, stream>>>(W1, W1h);

    // MFMA GEMM1 with split-K partials, then fused reduce+bias+relu
    gemm1_kernel<<<dim3(2, 16, NZ_), 256, 0, stream>>>(hadBK, W1h, part);
    reduce_kernel<<<1024, 256, 0, stream>>>(part, b1, h1);

    gemm23_kernel<<<B_, 128, 0, stream>>>(h1, W2, b2, W3, b3, out);
}

// Round 3
// 618.543 us; speedup vs baseline: 1.6478x; 1.2779x over previous
//
#include <hip/hip_runtime.h>
#include <hip/hip_fp16.h>

#define G_   20000
#define B_   256
#define NNZ_ 640000
#define KCH_ 640       // gemm1 split-K chunk (20 steps of 32; z=31 does 5)
#define NZ_  32        // split-K factor

typedef float f4 __attribute__((ext_vector_type(4)));
typedef _Float16 h8 __attribute__((ext_vector_type(8)));

// ---------------- zero scratch ------------------------------------------
__global__ __launch_bounds__(256) void zero_kernel(unsigned int* p, int n) {
    int i = blockIdx.x * 256 + threadIdx.x;
    if (i < n) p[i] = 0u;
}

// zero the meta padding tails (128 int2 each) so lockstep spmm overrun
// reads are harmless (v is predicated to 0, offset 0 is a valid row)
__global__ __launch_bounds__(256) void pad_kernel(int* pA, int* pB) {
    int t = threadIdx.x;
    pA[t] = 0; pB[t] = 0;
}

// ---------------- embed + transpose: [B,G] f32 -> [G,B] f16 --------------
__global__ __launch_bounds__(256) void embed_kernel(
        const float* __restrict__ xsamp, const float* __restrict__ xtf,
        const float* __restrict__ em, const float* __restrict__ bm,
        const float* __restrict__ ee, const float* __restrict__ be,
        __half* __restrict__ X0s, __half* __restrict__ X0t) {
    __shared__ float lds[64][65];       // [b][g]
    const int t  = threadIdx.x;
    const int gb = blockIdx.x * 64, bb = blockIdx.y * 64;
    const float a_m = em[0], c_m = bm[0], a_e = ee[0], c_e = be[0];
    const int gl = t & 63, brow0 = t >> 6;     // load mapping
    const int cl = t & 31, row0  = t >> 5;     // store mapping
    const int g_l = gb + gl;
    // ---- x_sample ----
#pragma unroll
    for (int r = 0; r < 16; r++) {
        int bl = brow0 + r * 4;
        float v = 0.f;
        if (g_l < G_) v = xsamp[(size_t)(bb + bl) * G_ + g_l];
        lds[bl][gl] = fmaxf(a_m * v + c_m, 0.f);
    }
    __syncthreads();
#pragma unroll
    for (int r = 0; r < 8; r++) {
        int gl2 = row0 + r * 8;
        int g = gb + gl2;
        if (g < G_) {
            __half2 hv = __floats2half2_rn(lds[cl * 2][gl2], lds[cl * 2 + 1][gl2]);
            *(__half2*)(X0s + (size_t)g * B_ + bb + cl * 2) = hv;
        }
    }
    __syncthreads();
    // ---- x_TF ----
#pragma unroll
    for (int r = 0; r < 16; r++) {
        int bl = brow0 + r * 4;
        float v = 0.f;
        if (g_l < G_) v = xtf[(size_t)(bb + bl) * G_ + g_l];
        lds[bl][gl] = fmaxf(a_e * v + c_e, 0.f);
    }
    __syncthreads();
#pragma unroll
    for (int r = 0; r < 8; r++) {
        int gl2 = row0 + r * 8;
        int g = gb + gl2;
        if (g < G_) {
            __half2 hv = __floats2half2_rn(lds[cl * 2][gl2], lds[cl * 2 + 1][gl2]);
            *(__half2*)(X0t + (size_t)g * B_ + bb + cl * 2) = hv;
        }
    }
}

// ---------------- CSR build ---------------------------------------------
__global__ __launch_bounds__(256) void hist_kernel(
        const int* __restrict__ rA, const int* __restrict__ rB,
        int* __restrict__ cntA, int* __restrict__ cntB) {
    int i = blockIdx.x * 256 + threadIdx.x;
    if (i < NNZ_) {
        atomicAdd(&cntA[rA[i]], 1);
        atomicAdd(&cntB[rB[i]], 1);
    }
}

__global__ __launch_bounds__(1024) void scan_kernel(
        const int* __restrict__ cntA, const int* __restrict__ cntB,
        int* __restrict__ rpA, int* __restrict__ rpB,
        int* __restrict__ curA, int* __restrict__ curB) {
    const int* cnt; int* rp; int* cur;
    if (blockIdx.x == 0) { cnt = cntA; rp = rpA; cur = curA; }
    else                 { cnt = cntB; rp = rpB; cur = curB; }
    __shared__ int lds[1024];
    const int t = threadIdx.x;
    const int CH = 20;
    int base = t * CH;
    int loc[CH];
    int s = 0;
#pragma unroll
    for (int i = 0; i < CH; i++) {
        int idx = base + i;
        int v = (idx < G_) ? cnt[idx] : 0;
        loc[i] = s; s += v;
    }
    lds[t] = s;
    __syncthreads();
    for (int off = 1; off < 1024; off <<= 1) {
        int v = lds[t];
        int add = (t >= off) ? lds[t - off] : 0;
        __syncthreads();
        lds[t] = v + add;
        __syncthreads();
    }
    int pre = (t == 0) ? 0 : lds[t - 1];
#pragma unroll
    for (int i = 0; i < CH; i++) {
        int idx = base + i;
        if (idx < G_) { int p = pre + loc[i]; rp[idx] = p; cur[idx] = p; }
    }
    if (t == 1023) rp[G_] = lds[1023];
}

// scatter packed meta: x = col byte-offset (c*512), y = bits(0.9*val)
__global__ __launch_bounds__(256) void scatter_kernel(
        const int* __restrict__ rA, const int* __restrict__ cA, const float* __restrict__ vA,
        const int* __restrict__ rB, const int* __restrict__ cB, const float* __restrict__ vB,
        int* __restrict__ curA, int* __restrict__ curB,
        int2* __restrict__ metaA, int2* __restrict__ metaB) {
    int i = blockIdx.x * 256 + threadIdx.x;
    if (i < NNZ_) {
        int r = rA[i]; int p = atomicAdd(&curA[r], 1);
        metaA[p] = make_int2(cA[i] * (B_ * 2), __float_as_int(0.9f * vA[i]));
        r = rB[i];     p = atomicAdd(&curB[r], 1);
        metaB[p] = make_int2(cB[i] * (B_ * 2), __float_as_int(0.9f * vB[i]));
    }
}

// ---------------- SPMM f16, 64-col chunks, XCD-affine --------------------
// 20000 blocks x 256 thr. combo = bid%8 -> (matrix, chunk) so each XCD's
// round-robin share keeps one 2.56MB x-chunk L2-resident. Half-wave per
// row, each lane 2 cols (half2 gather). vals pre-scaled by 0.9.
__global__ __launch_bounds__(256) void spmm_kernel(
        const int* __restrict__ rpA, const int2* __restrict__ metaA,
        const __half* __restrict__ xinA, __half* __restrict__ xoutA,
        const int* __restrict__ rpB, const int2* __restrict__ metaB,
        const __half* __restrict__ xinB, __half* __restrict__ xoutB) {
    const int bid   = blockIdx.x;
    const int combo = bid & 7;
    const int rowblk = bid >> 3;
    const int chunk = combo & 3;
    const int t = threadIdx.x;
    const int wave = t >> 6, lane = t & 63;
    const int half = lane >> 5, cl = lane & 31;
    const int g = rowblk * 8 + wave * 2 + half;
    const int loff = chunk * 128 + cl * 4;       // byte offset within x row
    const int* rp; const int2* meta; const __half* xin; __half* xout;
    if (combo < 4) { rp = rpA; meta = metaA; xin = xinA; xout = xoutA; }
    else           { rp = rpB; meta = metaB; xin = xinB; xout = xoutB; }
    int beg = rp[g];
    int n   = rp[g + 1] - beg;
    int nother = __shfl_xor(n, 32);
    int nmax = n > nother ? n : nother;
    const char* xb = (const char*)xin + loff;
    float ax = 0.f, ay = 0.f;
    int e = 0;
    for (; e + 4 <= nmax; e += 4) {
        int2 m0 = meta[beg + e],     m1 = meta[beg + e + 1];
        int2 m2 = meta[beg + e + 2], m3 = meta[beg + e + 3];
        float v0 = (e + 0 < n) ? __int_as_float(m0.y) : 0.f;
        float v1 = (e + 1 < n) ? __int_as_float(m1.y) : 0.f;
        float v2 = (e + 2 < n) ? __int_as_float(m2.y) : 0.f;
        float v3 = (e + 3 < n) ? __int_as_float(m3.y) : 0.f;
        float2 x0 = __half22float2(*(const __half2*)(xb + m0.x));
        float2 x1 = __half22float2(*(const __half2*)(xb + m1.x));
        float2 x2 = __half22float2(*(const __half2*)(xb + m2.x));
        float2 x3 = __half22float2(*(const __half2*)(xb + m3.x));
        ax = fmaf(v0, x0.x, ax); ay = fmaf(v0, x0.y, ay);
        ax = fmaf(v1, x1.x, ax); ay = fmaf(v1, x1.y, ay);
        ax = fmaf(v2, x2.x, ax); ay = fmaf(v2, x2.y, ay);
        ax = fmaf(v3, x3.x, ax); ay = fmaf(v3, x3.y, ay);
    }
    for (; e < nmax; ++e) {
        int2 m = meta[beg + e];
        float v = (e < n) ? __int_as_float(m.y) : 0.f;
        float2 x = __half22float2(*(const __half2*)(xb + m.x));
        ax = fmaf(v, x.x, ax); ay = fmaf(v, x.y, ay);
    }
    *(__half2*)((char*)xout + (size_t)g * (B_ * 2) + loff) = __floats2half2_rn(ax, ay);
}

// ---------------- combine + transpose + f16: -> had[b][g] ----------------
__global__ __launch_bounds__(256) void combine_kernel(
        const __half* __restrict__ X2s, const __half* __restrict__ X0s,
        const __half* __restrict__ X2t, const __half* __restrict__ X0t,
        __half* __restrict__ hadBK) {
    __shared__ float lds[64][65];       // [g][b]
    const int t = threadIdx.x;
    const int gb = blockIdx.x * 64, bb = blockIdx.y * 64;
    const int cl = t & 31, row0 = t >> 5;
#pragma unroll
    for (int r = 0; r < 8; r++) {
        int gl = row0 + r * 8;
        int g = gb + gl;
        float px = 0.f, py = 0.f;
        if (g < G_) {
            size_t idx = (size_t)g * B_ + bb + cl * 2;
            float2 x2s = __half22float2(*(const __half2*)(X2s + idx));
            float2 x0s = __half22float2(*(const __half2*)(X0s + idx));
            float2 x2t = __half22float2(*(const __half2*)(X2t + idx));
            float2 x0t = __half22float2(*(const __half2*)(X0t + idx));
            px = (x2s.x + 0.1f * x0s.x) * (x2t.x + 0.1f * x0t.x);
            py = (x2s.y + 0.1f * x0s.y) * (x2t.y + 0.1f * x0t.y);
        }
        lds[gl][cl * 2]     = px;
        lds[gl][cl * 2 + 1] = py;
    }
    __syncthreads();
#pragma unroll
    for (int r = 0; r < 8; r++) {
        int bl = row0 + r * 8;
        int g0 = gb + cl * 2;
        if (g0 < G_) {
            __half2 hv = __floats2half2_rn(lds[cl * 2][bl], lds[cl * 2 + 1][bl]);
            *(__half2*)(hadBK + (size_t)(bb + bl) * G_ + g0) = hv;
        }
    }
}

// ---------------- GEMM1 MFMA f16: part[z][b][o] --------------------------
// tile 256(b) x 128(o) x BK32, 512 thr = 8 waves (4 b-quads x 2 o-halves),
// W1 read as f32 and converted in staging (W1 read exactly once overall).
__global__ __launch_bounds__(512) void gemm1_kernel(
        const __half* __restrict__ hadBK, const float* __restrict__ W1,
        float* __restrict__ part) {
    __shared__ _Float16 a_lds[256][40];   // stride 80B = 16B-aligned, 2-way banks
    __shared__ _Float16 b_lds[128][40];
    const int t = threadIdx.x;
    const int lane = t & 63, wid = t >> 6;
    const int wm = wid >> 1, wn = wid & 1;
    const int l15 = lane & 15, l4 = lane >> 4;
    const int ob = blockIdx.x * 128;
    const int kb = blockIdx.y * KCH_;
    int kend = kb + KCH_; if (kend > G_) kend = G_;
    const int nsteps = (kend - kb) >> 5;       // 20, or 5 at z=31
    const int ar = t >> 1, ah = t & 1;
    const int br = t >> 2, bs = t & 3;
    const _Float16* hadH = (const _Float16*)hadBK;
    f4 acc[4][4] = {};
    for (int s = 0; s < nsteps; ++s) {
        const int k0 = kb + s * 32;
        {   // stage A: hadBK rows (b)
            const _Float16* src = hadH + (size_t)ar * G_ + k0 + ah * 16;
            *(h8*)&a_lds[ar][ah * 16]     = *(const h8*)(src);
            *(h8*)&a_lds[ar][ah * 16 + 8] = *(const h8*)(src + 8);
        }
        {   // stage B: W1 f32 rows (o), convert to f16
            const float* src = W1 + (size_t)(ob + br) * G_ + k0 + bs * 8;
            f4 w0 = *(const f4*)src;
            f4 w1 = *(const f4*)(src + 4);
            h8 h;
            h[0] = (_Float16)w0[0]; h[1] = (_Float16)w0[1];
            h[2] = (_Float16)w0[2]; h[3] = (_Float16)w0[3];
            h[4] = (_Float16)w1[0]; h[5] = (_Float16)w1[1];
            h[6] = (_Float16)w1[2]; h[7] = (_Float16)w1[3];
            *(h8*)&b_lds[br][bs * 8] = h;
        }
        __syncthreads();
        h8 af[4], bf[4];
#pragma unroll
        for (int m = 0; m < 4; m++)
            af[m] = *(const h8*)&a_lds[wm * 64 + m * 16 + l15][l4 * 8];
#pragma unroll
        for (int n = 0; n < 4; n++)
            bf[n] = *(const h8*)&b_lds[wn * 64 + n * 16 + l15][l4 * 8];
#pragma unroll
        for (int m = 0; m < 4; m++)
#pragma unroll
            for (int n = 0; n < 4; n++)
                acc[m][n] = __builtin_amdgcn_mfma_f32_16x16x32_f16(
                    af[m], bf[n], acc[m][n], 0, 0, 0);
        __syncthreads();
    }
    const size_t zoff = (size_t)blockIdx.y * (B_ * 1024);
#pragma unroll
    for (int m = 0; m < 4; m++)
#pragma unroll
        for (int n = 0; n < 4; n++)
#pragma unroll
            for (int j = 0; j < 4; j++) {
                int b = wm * 64 + m * 16 + l4 * 4 + j;
                int o = ob + wn * 64 + n * 16 + l15;
                part[zoff + (size_t)b * 1024 + o] = acc[m][n][j];
            }
}

// ---------------- reduce split-K + bias + relu -> h1 ---------------------
__global__ __launch_bounds__(256) void reduce_kernel(
        const float* __restrict__ part, const float* __restrict__ b1,
        float* __restrict__ h1) {
    int i = blockIdx.x * 256 + threadIdx.x;    // 262144 total
    float s = 0.f;
#pragma unroll
    for (int z = 0; z < NZ_; z++) s += part[(size_t)z * 262144 + i];
    h1[i] = fmaxf(s + b1[i & 1023], 0.f);
}

// ---------------- fused GEMM2 (relu) + GEMM3 -----------------------------
__global__ __launch_bounds__(128) void gemm23_kernel(
        const float* __restrict__ h1, const float* __restrict__ W2,
        const float* __restrict__ b2, const float* __restrict__ W3,
        const float* __restrict__ b3, float* __restrict__ out) {
    __shared__ float h1row[1024];
    __shared__ float h2[128];
    const int b = blockIdx.x, t = threadIdx.x;
    *(f4*)&h1row[t * 4]       = *(const f4*)(h1 + (size_t)b * 1024 + t * 4);
    *(f4*)&h1row[512 + t * 4] = *(const f4*)(h1 + (size_t)b * 1024 + 512 + t * 4);
    __syncthreads();
    {
        float acc = b2[t];
        const f4* w  = (const f4*)(W2 + (size_t)t * 1024);
        const f4* hr = (const f4*)h1row;
        for (int k = 0; k < 256; k++) {
            f4 wv = w[k], hv = hr[k];
            acc += wv[0] * hv[0] + wv[1] * hv[1] + wv[2] * hv[2] + wv[3] * hv[3];
        }
        h2[t] = fmaxf(acc, 0.f);
    }
    __syncthreads();
    if (t < 33) {
        float acc = b3[t];
        const f4* w  = (const f4*)(W3 + (size_t)t * 128);
        const f4* hv = (const f4*)h2;
#pragma unroll
        for (int k = 0; k < 32; k++) {
            f4 a = w[k], x = hv[k];
            acc += a[0] * x[0] + a[1] * x[1] + a[2] * x[2] + a[3] * x[3];
        }
        out[b * 33 + t] = acc;
    }
}

extern "C" void kernel_launch(void* const* d_in, const int* in_sizes, int n_in,
                              void* d_out, int out_size, void* d_ws, size_t ws_size,
                              hipStream_t stream) {
    const float* x_sample  = (const float*)d_in[0];
    const float* x_TF      = (const float*)d_in[1];
    const int*   adj_rows  = (const int*)d_in[2];
    const int*   adj_cols  = (const int*)d_in[3];
    const float* adj_vals  = (const float*)d_in[4];
    const int*   adjT_rows = (const int*)d_in[5];
    const int*   adjT_cols = (const int*)d_in[6];
    const float* adjT_vals = (const float*)d_in[7];
    const float* emb_mut   = (const float*)d_in[8];
    const float* bias_mut  = (const float*)d_in[9];
    const float* emb_exp   = (const float*)d_in[10];
    const float* bias_exp  = (const float*)d_in[11];
    const float* W1 = (const float*)d_in[12];
    const float* b1 = (const float*)d_in[13];
    const float* W2 = (const float*)d_in[14];
    const float* b2 = (const float*)d_in[15];
    const float* W3 = (const float*)d_in[16];
    const float* b3 = (const float*)d_in[17];
    float* out = (float*)d_out;

    // ---- workspace layout (~107 MB) ----
    char* w = (char*)d_ws;
    auto alloc = [&](size_t bytes) {
        char* p = w; w += (bytes + 255) & ~(size_t)255; return p;
    };
    __half* X0s = (__half*)alloc(5120000 * 2);
    __half* X1s = (__half*)alloc(5120000 * 2);
    __half* X2s = (__half*)alloc(5120000 * 2);
    __half* X0t = (__half*)alloc(5120000 * 2);
    __half* X1t = (__half*)alloc(5120000 * 2);
    __half* X2t = (__half*)alloc(5120000 * 2);
    float*  part = (float*)alloc((size_t)NZ_ * 262144 * 4);   // 33.5 MB
    float*  h1   = (float*)alloc(262144 * 4);
    int2*   metaA = (int2*)alloc((NNZ_ + 128) * 8);
    int2*   metaB = (int2*)alloc((NNZ_ + 128) * 8);
    int*    cnt  = (int*)alloc(40000 * 4);     // cntA|cntB contiguous
    int*    cntA = cnt;
    int*    cntB = cnt + 20000;
    int*    rpA  = (int*)alloc(20001 * 4);
    int*    rpB  = (int*)alloc(20001 * 4);
    int*    curA = (int*)alloc(20000 * 4);
    int*    curB = (int*)alloc(20000 * 4);
    __half* hadBK = X1s;    // overlay: X1s dead after spmm iter 2

    zero_kernel<<<157, 256, 0, stream>>>((unsigned int*)cnt, 40000);
    pad_kernel<<<1, 256, 0, stream>>>((int*)(metaA + NNZ_), (int*)(metaB + NNZ_));

    embed_kernel<<<dim3(313, 4), 256, 0, stream>>>(
        x_sample, x_TF, emb_mut, bias_mut, emb_exp, bias_exp, X0s, X0t);

    hist_kernel<<<2500, 256, 0, stream>>>(adj_rows, adjT_rows, cntA, cntB);
    scan_kernel<<<2, 1024, 0, stream>>>(cntA, cntB, rpA, rpB, curA, curB);
    scatter_kernel<<<2500, 256, 0, stream>>>(
        adj_rows, adj_cols, adj_vals, adjT_rows, adjT_cols, adjT_vals,
        curA, curB, metaA, metaB);

    // K = 2 PPR iterations (0.9 folded into vals)
    spmm_kernel<<<20000, 256, 0, stream>>>(rpA, metaA, X0s, X1s,
                                           rpB, metaB, X0t, X1t);
    spmm_kernel<<<20000, 256, 0, stream>>>(rpA, metaA, X1s, X2s,
                                           rpB, metaB, X1t, X2t);

    combine_kernel<<<dim3(313, 4), 256, 0, stream>>>(X2s, X0s, X2t, X0t, hadBK);

    gemm1_kernel<<<dim3(8, NZ_), 512, 0, stream>>>(hadBK, W1, part);
    reduce_kernel<<<1024, 256, 0, stream>>>(part, b1, h1);
    gemm23_kernel<<<B_, 128, 0, stream>>>(h1, W2, b2, W3, b3, out);
}